// Round 1
// baseline (1098.400 us; speedup 1.0000x reference)
//
#include <hip/hip_runtime.h>

#define N_ROWS 262144
#define HID 512
#define HHALF 256
#define HEADS 8
#define GNUM 1024
#define LN_EPS 1e-5f
#define POOL_ROWS 128

typedef __bf16 bf16x8 __attribute__((ext_vector_type(8)));
typedef float f32x4 __attribute__((ext_vector_type(4)));

// ---------------- kernel 0: W1^T -> bf16, zero entropy slot + graph_z ----------------
__global__ void k_prep(const float* __restrict__ W1, __bf16* __restrict__ w1t,
                       float* __restrict__ ent, float* __restrict__ graph_z) {
    int tid = blockIdx.x * 256 + threadIdx.x;
    if (tid == 0) *ent = 0.f;
    // zero graph_z: 131072 threads x float4 = 524288 floats = G*HID exactly
    ((float4*)graph_z)[tid] = make_float4(0.f, 0.f, 0.f, 0.f);
    if (tid < HID * HHALF) {
        int n = tid >> 9;   // 0..255 (output feature)
        int k = tid & 511;  // 0..511 (input feature)
        w1t[n * HID + k] = (__bf16)W1[k * HHALF + n];
    }
}

// ---------------- kernel 0b: segment starts (batch is sorted) ----------------
__global__ void k_seg(const int* __restrict__ batch, int* __restrict__ seg) {
    int g = blockIdx.x * 256 + threadIdx.x;
    if (g > GNUM) return;
    int lo = 0, hi = N_ROWS;
    while (lo < hi) {
        int mid = (lo + hi) >> 1;
        if (batch[mid] < g) lo = mid + 1; else hi = mid;
    }
    seg[g] = lo;
}

// ---------------- kernel 1: LayerNorm stats per row (1 wave = 1 row) ----------------
__global__ __launch_bounds__(256) void k_stats(const float* __restrict__ x,
                                               float2* __restrict__ stats) {
    int wid = threadIdx.x >> 6, lane = threadIdx.x & 63;
    int row = blockIdx.x * 4 + wid;
    const float* xr = x + (size_t)row * HID + lane * 8;
    float4 a = *(const float4*)xr;
    float4 b = *(const float4*)(xr + 4);
    float s = a.x + a.y + a.z + a.w + b.x + b.y + b.z + b.w;
    float q = a.x*a.x + a.y*a.y + a.z*a.z + a.w*a.w
            + b.x*b.x + b.y*b.y + b.z*b.z + b.w*b.w;
    #pragma unroll
    for (int m = 1; m < 64; m <<= 1) {
        s += __shfl_xor(s, m);
        q += __shfl_xor(q, m);
    }
    if (lane == 0) {
        float mu = s * (1.f / HID);
        float var = q * (1.f / HID) - mu * mu;
        stats[row] = make_float2(mu, rsqrtf(var + LN_EPS));
    }
}

// A-fragment build: load 8 f32, apply LN (x*rstd - mu*rstd)*gamma + beta, cast bf16
__device__ inline bf16x8 make_af(const float* xp, const float* gp, const float* bp,
                                 float rstd, float nmr) {
    float4 xa = *(const float4*)xp;
    float4 xb = *(const float4*)(xp + 4);
    float4 ga = *(const float4*)gp;
    float4 gb = *(const float4*)(gp + 4);
    float4 ba = *(const float4*)bp;
    float4 bb = *(const float4*)(bp + 4);
    float xs[8] = {xa.x, xa.y, xa.z, xa.w, xb.x, xb.y, xb.z, xb.w};
    float gs[8] = {ga.x, ga.y, ga.z, ga.w, gb.x, gb.y, gb.z, gb.w};
    float bs[8] = {ba.x, ba.y, ba.z, ba.w, bb.x, bb.y, bb.z, bb.w};
    bf16x8 r;
    #pragma unroll
    for (int j = 0; j < 8; ++j)
        r[j] = (__bf16)fmaf(fmaf(xs[j], rstd, nmr), gs[j], bs[j]);
    return r;
}

// ---------------- kernel 2: fused LN-apply + GEMM(512->256) + silu + W2 -> logits ----------------
__global__ __launch_bounds__(256) void k_gemm(
    const float* __restrict__ x, const float2* __restrict__ stats,
    const float* __restrict__ gamma, const float* __restrict__ beta,
    const __bf16* __restrict__ w1t, const float* __restrict__ b1,
    const float* __restrict__ W2, const float* __restrict__ b2,
    float* __restrict__ logits)
{
    __shared__ __align__(16) __bf16 ldsb[256 * 72];
    const int tid = threadIdx.x;
    const int wid = tid >> 6, lane = tid & 63;
    const int q = lane >> 4, c = lane & 15;
    const int rowbase = blockIdx.x * 64 + wid * 16;

    f32x4 acc[16];
    #pragma unroll
    for (int t = 0; t < 16; ++t) acc[t] = (f32x4)0.f;

    const int arow = rowbase + c;
    float2 st = stats[arow];
    const float rstd = st.y;
    const float nmr = -st.x * st.y;
    const float* xrow = x + (size_t)arow * HID;

    const int nrow = tid >> 3, seg = tid & 7;

    for (int s8 = 0; s8 < 8; ++s8) {
        const int k0 = s8 * 64;
        __syncthreads();
        #pragma unroll
        for (int it = 0; it < 8; ++it) {
            int n = nrow + it * 32;
            *(uint4*)(ldsb + n * 72 + seg * 8) =
                *(const uint4*)(w1t + n * HID + k0 + seg * 8);
        }
        __syncthreads();

        bf16x8 af0 = make_af(xrow + k0 + q * 8, gamma + k0 + q * 8, beta + k0 + q * 8,
                             rstd, nmr);
        bf16x8 af1 = make_af(xrow + k0 + 32 + q * 8, gamma + k0 + 32 + q * 8,
                             beta + k0 + 32 + q * 8, rstd, nmr);
        #pragma unroll
        for (int t = 0; t < 16; ++t) {
            int n = t * 16 + c;
            bf16x8 bf0 = *(const bf16x8*)(ldsb + n * 72 + q * 8);
            bf16x8 bf1 = *(const bf16x8*)(ldsb + n * 72 + 32 + q * 8);
            acc[t] = __builtin_amdgcn_mfma_f32_16x16x32_bf16(af0, bf0, acc[t], 0, 0, 0);
            acc[t] = __builtin_amdgcn_mfma_f32_16x16x32_bf16(af1, bf1, acc[t], 0, 0, 0);
        }
    }

    float lp[4][8];
    #pragma unroll
    for (int r = 0; r < 4; ++r)
        #pragma unroll
        for (int hd = 0; hd < 8; ++hd) lp[r][hd] = 0.f;

    #pragma unroll
    for (int t = 0; t < 16; ++t) {
        int n = t * 16 + c;
        float b1v = b1[n];
        float4 w2a = *(const float4*)(W2 + n * 8);
        float4 w2b = *(const float4*)(W2 + n * 8 + 4);
        #pragma unroll
        for (int r = 0; r < 4; ++r) {
            float v = acc[t][r] + b1v;
            float h = v / (1.f + __expf(-v));
            lp[r][0] = fmaf(h, w2a.x, lp[r][0]);
            lp[r][1] = fmaf(h, w2a.y, lp[r][1]);
            lp[r][2] = fmaf(h, w2a.z, lp[r][2]);
            lp[r][3] = fmaf(h, w2a.w, lp[r][3]);
            lp[r][4] = fmaf(h, w2b.x, lp[r][4]);
            lp[r][5] = fmaf(h, w2b.y, lp[r][5]);
            lp[r][6] = fmaf(h, w2b.z, lp[r][6]);
            lp[r][7] = fmaf(h, w2b.w, lp[r][7]);
        }
    }
    #pragma unroll
    for (int m = 1; m < 16; m <<= 1)
        #pragma unroll
        for (int r = 0; r < 4; ++r)
            #pragma unroll
            for (int hd = 0; hd < 8; ++hd)
                lp[r][hd] += __shfl_xor(lp[r][hd], m);

    if (c == 0) {
        float4 b2a = *(const float4*)b2;
        float4 b2b = *(const float4*)(b2 + 4);
        #pragma unroll
        for (int r = 0; r < 4; ++r) {
            int orow = rowbase + q * 4 + r;
            float4 o0 = {lp[r][0] + b2a.x, lp[r][1] + b2a.y,
                         lp[r][2] + b2a.z, lp[r][3] + b2a.w};
            float4 o1 = {lp[r][4] + b2b.x, lp[r][5] + b2b.y,
                         lp[r][6] + b2b.z, lp[r][7] + b2b.w};
            *(float4*)(logits + (size_t)orow * 8) = o0;
            *(float4*)(logits + (size_t)orow * 8 + 4) = o1;
        }
    }
}

// ---------------- kernel 3a: per-graph softmax stats (max + sum tables) ----------------
__global__ __launch_bounds__(256) void k_smax(
    const float* __restrict__ logits, const int* __restrict__ seg,
    float* __restrict__ smaxt, float* __restrict__ sinvt)
{
    const int g = blockIdx.x;
    const int tid = threadIdx.x;
    const int s = seg[g], e = seg[g + 1];
    __shared__ float red[4][8];
    __shared__ float smx[8];
    const int wid = tid >> 6, lane = tid & 63;

    if (e <= s) {
        if (tid < 8) { smaxt[g * 8 + tid] = 0.f; sinvt[g * 8 + tid] = 1.f; }
        return;
    }
    // ---- phase A: per-head max
    float mx[8];
    #pragma unroll
    for (int h = 0; h < 8; ++h) mx[h] = -1e30f;
    for (int i = s + tid; i < e; i += 256) {
        float4 l0 = *(const float4*)(logits + (size_t)i * 8);
        float4 l1 = *(const float4*)(logits + (size_t)i * 8 + 4);
        mx[0] = fmaxf(mx[0], l0.x); mx[1] = fmaxf(mx[1], l0.y);
        mx[2] = fmaxf(mx[2], l0.z); mx[3] = fmaxf(mx[3], l0.w);
        mx[4] = fmaxf(mx[4], l1.x); mx[5] = fmaxf(mx[5], l1.y);
        mx[6] = fmaxf(mx[6], l1.z); mx[7] = fmaxf(mx[7], l1.w);
    }
    #pragma unroll
    for (int m = 1; m < 64; m <<= 1)
        #pragma unroll
        for (int h = 0; h < 8; ++h) mx[h] = fmaxf(mx[h], __shfl_xor(mx[h], m));
    if (lane == 0) {
        #pragma unroll
        for (int h = 0; h < 8; ++h) red[wid][h] = mx[h];
    }
    __syncthreads();
    if (tid < 8)
        smx[tid] = fmaxf(fmaxf(red[0][tid], red[1][tid]),
                         fmaxf(red[2][tid], red[3][tid]));
    __syncthreads();
    // ---- phase B: sum of exp
    float sm[8];
    #pragma unroll
    for (int h = 0; h < 8; ++h) sm[h] = smx[h];
    float su[8] = {0, 0, 0, 0, 0, 0, 0, 0};
    for (int i = s + tid; i < e; i += 256) {
        float4 l0 = *(const float4*)(logits + (size_t)i * 8);
        float4 l1 = *(const float4*)(logits + (size_t)i * 8 + 4);
        su[0] += __expf(l0.x - sm[0]); su[1] += __expf(l0.y - sm[1]);
        su[2] += __expf(l0.z - sm[2]); su[3] += __expf(l0.w - sm[3]);
        su[4] += __expf(l1.x - sm[4]); su[5] += __expf(l1.y - sm[5]);
        su[6] += __expf(l1.z - sm[6]); su[7] += __expf(l1.w - sm[7]);
    }
    #pragma unroll
    for (int m = 1; m < 64; m <<= 1)
        #pragma unroll
        for (int h = 0; h < 8; ++h) su[h] += __shfl_xor(su[h], m);
    if (lane == 0) {
        #pragma unroll
        for (int h = 0; h < 8; ++h) red[wid][h] = su[h];
    }
    __syncthreads();
    if (tid < 8) {
        float d = red[0][tid] + red[1][tid] + red[2][tid] + red[3][tid];
        smaxt[g * 8 + tid] = smx[tid];
        sinvt[g * 8 + tid] = 1.f / (d > 0.f ? d : 1.f);
    }
}

// ---------------- kernel 3b: weights + entropy (row-parallel, coalesced) ----------------
__global__ __launch_bounds__(256) void k_wts(
    const float* __restrict__ logits, const int* __restrict__ batch,
    const float* __restrict__ smaxt, const float* __restrict__ sinvt,
    float* __restrict__ weights, float* __restrict__ ent)
{
    const int tid = threadIdx.x;
    const int i0 = blockIdx.x * 256;      // 256 rows per block
    const int h = tid & 7;
    float e = 0.f;
    #pragma unroll
    for (int it = 0; it < 8; ++it) {
        int i = i0 + (tid >> 3) + it * 32;
        int g = batch[i];
        float l = logits[(size_t)i * 8 + h];
        float w = __expf(l - smaxt[g * 8 + h]) * sinvt[g * 8 + h];
        weights[(size_t)i * 8 + h] = w;
        e += w * __logf(w + 1e-8f);
    }
    #pragma unroll
    for (int m = 1; m < 64; m <<= 1) e += __shfl_xor(e, m);
    __shared__ float red[4];
    if ((tid & 63) == 0) red[tid >> 6] = e;
    __syncthreads();
    if (tid == 0)
        atomicAdd(ent, (red[0] + red[1] + red[2] + red[3]) * (-1.f / (GNUM * 8.f)));
}

// ---------------- kernel 3c: weighted pooling, row-chunked scatter-add ----------------
// 2048 blocks x 256 thr; each block streams 128 rows; thread owns features 2t,2t+1.
// batch is sorted -> accumulate in registers, flush on graph boundary via atomicAdd.
__global__ __launch_bounds__(256) void k_pool2(
    const float* __restrict__ x, const int* __restrict__ batch,
    const float* __restrict__ weights, float* __restrict__ graph_z)
{
    const int tid = threadIdx.x;
    const int r0 = blockIdx.x * POOL_ROWS;
    const int h = tid >> 5;                    // head of feature 2*tid
    const int f = tid * 2;
    float a0 = 0.f, a1 = 0.f;
    int gcur = batch[r0];
    const int gend = batch[r0 + POOL_ROWS - 1];

    if (gcur == gend) {
        // fast path: whole chunk in one graph -> branch-free unrolled stream
        #pragma unroll 4
        for (int r = 0; r < POOL_ROWS; ++r) {
            const size_t i = (size_t)(r0 + r);
            float2 xv = *(const float2*)(x + i * HID + f);
            float w = weights[i * 8 + h];
            a0 = fmaf(xv.x, w, a0);
            a1 = fmaf(xv.y, w, a1);
        }
        atomicAdd(graph_z + (size_t)gcur * HID + f, a0);
        atomicAdd(graph_z + (size_t)gcur * HID + f + 1, a1);
    } else {
        for (int r = 0; r < POOL_ROWS; ++r) {
            const int i = r0 + r;
            const int g = batch[i];
            if (g != gcur) {
                atomicAdd(graph_z + (size_t)gcur * HID + f, a0);
                atomicAdd(graph_z + (size_t)gcur * HID + f + 1, a1);
                a0 = 0.f; a1 = 0.f; gcur = g;
            }
            float2 xv = *(const float2*)(x + (size_t)i * HID + f);
            float w = weights[(size_t)i * 8 + h];
            a0 = fmaf(xv.x, w, a0);
            a1 = fmaf(xv.y, w, a1);
        }
        atomicAdd(graph_z + (size_t)gcur * HID + f, a0);
        atomicAdd(graph_z + (size_t)gcur * HID + f + 1, a1);
    }
}

extern "C" void kernel_launch(void* const* d_in, const int* in_sizes, int n_in,
                              void* d_out, int out_size, void* d_ws, size_t ws_size,
                              hipStream_t stream)
{
    const float* x     = (const float*)d_in[0];
    const int*   batch = (const int*)d_in[1];
    const float* gamma = (const float*)d_in[2];
    const float* beta  = (const float*)d_in[3];
    const float* W1    = (const float*)d_in[4];
    const float* b1    = (const float*)d_in[5];
    const float* W2    = (const float*)d_in[6];
    const float* b2    = (const float*)d_in[7];

    char* ws = (char*)d_ws;
    float2* stats  = (float2*)ws;                                   // 2 MB
    float*  logits = (float*)(ws + (size_t)2 * 1024 * 1024);        // 8 MB
    __bf16* w1t    = (__bf16*)(ws + (size_t)10 * 1024 * 1024);      // 256 KB
    int*    seg    = (int*)(ws + (size_t)10 * 1024 * 1024 + 256 * 1024); // 4.1 KB
    float*  smaxt  = (float*)(ws + (size_t)10 * 1024 * 1024 + 512 * 1024); // 32 KB
    float*  sinvt  = (float*)(ws + (size_t)10 * 1024 * 1024 + 576 * 1024); // 32 KB

    float* out     = (float*)d_out;
    float* graph_z = out;                                           // [G,512]
    float* weights = out + (size_t)GNUM * HID;                      // [N,8]
    float* ent     = out + (size_t)GNUM * HID + (size_t)N_ROWS * HEADS; // scalar

    k_prep <<<512, 256, 0, stream>>>(W1, w1t, ent, graph_z);
    k_seg  <<<5, 256, 0, stream>>>(batch, seg);
    k_stats<<<N_ROWS / 4, 256, 0, stream>>>(x, stats);
    k_gemm <<<N_ROWS / 64, 256, 0, stream>>>(x, stats, gamma, beta, w1t, b1, W2, b2, logits);
    k_smax <<<GNUM, 256, 0, stream>>>(logits, seg, smaxt, sinvt);
    k_wts  <<<N_ROWS / 256, 256, 0, stream>>>(logits, batch, smaxt, sinvt, weights, ent);
    k_pool2<<<N_ROWS / POOL_ROWS, 256, 0, stream>>>(x, batch, weights, graph_z);
}

// Round 2
// 1012.111 us; speedup vs baseline: 1.0853x; 1.0853x over previous
//
#include <hip/hip_runtime.h>

#define N_ROWS 262144
#define HID 512
#define HHALF 256
#define HEADS 8
#define GNUM 1024
#define LN_EPS 1e-5f
#define POOL_ROWS 128

typedef __bf16 bf16x8 __attribute__((ext_vector_type(8)));
typedef float f32x4 __attribute__((ext_vector_type(4)));

// ---------------- kernel 0: w1t = bf16(gamma ⊙ W1)^T, zero ent/graph_z/G1/BB ----------------
__global__ void k_prep(const float* __restrict__ W1, const float* __restrict__ gamma,
                       __bf16* __restrict__ w1t, float* __restrict__ ent,
                       float* __restrict__ graph_z, float* __restrict__ G1,
                       float* __restrict__ BB) {
    int tid = blockIdx.x * 256 + threadIdx.x;
    if (tid == 0) *ent = 0.f;
    if (blockIdx.x == 0) { G1[threadIdx.x] = 0.f; BB[threadIdx.x] = 0.f; }
    // zero graph_z: 131072 threads x float4 = 524288 floats = G*HID exactly
    ((float4*)graph_z)[tid] = make_float4(0.f, 0.f, 0.f, 0.f);
    int n = tid >> 9;   // 0..255 (output feature)
    int k = tid & 511;  // 0..511 (input feature)
    w1t[n * HID + k] = (__bf16)(gamma[k] * W1[k * HHALF + n]);
}

// ---------------- kernel 0c: G1[n] = sum_k gamma[k]W1[k,n]; BB[n] = sum_k beta[k]W1[k,n] ----
__global__ void k_cols(const float* __restrict__ W1, const float* __restrict__ gamma,
                       const float* __restrict__ beta, float* __restrict__ G1,
                       float* __restrict__ BB) {
    int n = threadIdx.x;            // 0..255
    int k0 = blockIdx.x * 64;       // 8 blocks x 64 k each
    float g = 0.f, b = 0.f;
    #pragma unroll
    for (int kk = 0; kk < 64; ++kk) {
        int k = k0 + kk;
        float w = W1[(size_t)k * HHALF + n];
        g = fmaf(gamma[k], w, g);
        b = fmaf(beta[k], w, b);
    }
    atomicAdd(G1 + n, g);
    atomicAdd(BB + n, b);
}

// ---------------- kernel 0b: segment starts (batch is sorted) ----------------
__global__ void k_seg(const int* __restrict__ batch, int* __restrict__ seg) {
    int g = blockIdx.x * 256 + threadIdx.x;
    if (g > GNUM) return;
    int lo = 0, hi = N_ROWS;
    while (lo < hi) {
        int mid = (lo + hi) >> 1;
        if (batch[mid] < g) lo = mid + 1; else hi = mid;
    }
    seg[g] = lo;
}

__device__ inline bf16x8 pack8(float4 a, float4 b) {
    bf16x8 r;
    r[0] = (__bf16)a.x; r[1] = (__bf16)a.y; r[2] = (__bf16)a.z; r[3] = (__bf16)a.w;
    r[4] = (__bf16)b.x; r[5] = (__bf16)b.y; r[6] = (__bf16)b.z; r[7] = (__bf16)b.w;
    return r;
}

// ---------------- kernel 1: single-pass fused LN-GEMM + silu + W2 -> logits ----------------
// LN folded algebraically: x_norm@W1 = rstd*(x@(gamma.W1)) + (-mu*rstd)*G1 + BB.
// A-operand = raw bf16(x), loaded ONCE as a burst; stats from the same registers;
// main loop has zero global loads (w1t staged via LDS, af in registers).
__global__ __launch_bounds__(256) void k_gemm(
    const float* __restrict__ x,
    const __bf16* __restrict__ w1t, const float* __restrict__ b1,
    const float* __restrict__ G1, const float* __restrict__ BB,
    const float* __restrict__ W2, const float* __restrict__ b2,
    float* __restrict__ logits)
{
    __shared__ __align__(16) __bf16 ldsb[256 * 72];
    const int tid = threadIdx.x;
    const int wid = tid >> 6, lane = tid & 63;
    const int q = lane >> 4, c = lane & 15;
    const int rowbase = blockIdx.x * 64 + wid * 16;
    const float* xrow = x + (size_t)(rowbase + c) * HID;

    // ---- burst-load this lane's quarter-row of x, accumulate stats, pack A-frags
    bf16x8 af[8][2];
    float s = 0.f, qq = 0.f;
    #pragma unroll
    for (int s8 = 0; s8 < 8; ++s8) {
        float4 a = *(const float4*)(xrow + s8 * 64 + q * 8);
        float4 b = *(const float4*)(xrow + s8 * 64 + q * 8 + 4);
        float4 d = *(const float4*)(xrow + s8 * 64 + 32 + q * 8);
        float4 e = *(const float4*)(xrow + s8 * 64 + 32 + q * 8 + 4);
        s += a.x + a.y + a.z + a.w + b.x + b.y + b.z + b.w
           + d.x + d.y + d.z + d.w + e.x + e.y + e.z + e.w;
        qq = fmaf(a.x, a.x, qq); qq = fmaf(a.y, a.y, qq);
        qq = fmaf(a.z, a.z, qq); qq = fmaf(a.w, a.w, qq);
        qq = fmaf(b.x, b.x, qq); qq = fmaf(b.y, b.y, qq);
        qq = fmaf(b.z, b.z, qq); qq = fmaf(b.w, b.w, qq);
        qq = fmaf(d.x, d.x, qq); qq = fmaf(d.y, d.y, qq);
        qq = fmaf(d.z, d.z, qq); qq = fmaf(d.w, d.w, qq);
        qq = fmaf(e.x, e.x, qq); qq = fmaf(e.y, e.y, qq);
        qq = fmaf(e.z, e.z, qq); qq = fmaf(e.w, e.w, qq);
        af[s8][0] = pack8(a, b);
        af[s8][1] = pack8(d, e);
    }
    // full row-(rowbase+c) sums: reduce across the 4 q-lanes sharing c
    s  += __shfl_xor(s, 16);  s  += __shfl_xor(s, 32);
    qq += __shfl_xor(qq, 16); qq += __shfl_xor(qq, 32);
    const float mu = s * (1.f / HID);
    const float var = qq * (1.f / HID) - mu * mu;
    const float rstd = rsqrtf(var + LN_EPS);
    const float nmr = -mu * rstd;

    f32x4 acc[16];
    #pragma unroll
    for (int t = 0; t < 16; ++t) acc[t] = (f32x4)0.f;

    const int nrow = tid >> 3, sg = tid & 7;   // staging map: 8 thr per 128B row-chunk

    #pragma unroll
    for (int s8 = 0; s8 < 8; ++s8) {
        const int k0 = s8 * 64;
        __syncthreads();
        #pragma unroll
        for (int it = 0; it < 8; ++it) {
            int n = nrow + it * 32;
            *(uint4*)(ldsb + n * 72 + sg * 8) =
                *(const uint4*)(w1t + n * HID + k0 + sg * 8);
        }
        __syncthreads();
        #pragma unroll
        for (int t = 0; t < 16; ++t) {
            int n = t * 16 + c;
            bf16x8 bf0 = *(const bf16x8*)(ldsb + n * 72 + q * 8);
            bf16x8 bf1 = *(const bf16x8*)(ldsb + n * 72 + 32 + q * 8);
            acc[t] = __builtin_amdgcn_mfma_f32_16x16x32_bf16(af[s8][0], bf0, acc[t], 0, 0, 0);
            acc[t] = __builtin_amdgcn_mfma_f32_16x16x32_bf16(af[s8][1], bf1, acc[t], 0, 0, 0);
        }
    }

    // per-output-row LN scale: acc row (q*4+r) belongs to x-row rowbase+q*4+r,
    // whose stats live in the lane with c == q*4+r (same q group).
    float rstd_r[4], nmr_r[4];
    #pragma unroll
    for (int r = 0; r < 4; ++r) {
        int src = (lane & 48) | (q * 4 + r);
        rstd_r[r] = __shfl(rstd, src);
        nmr_r[r]  = __shfl(nmr, src);
    }

    // epilogue: h = silu(rstd*acc + nmr*G1 + BB + b1); logits partial = h @ W2
    float lp[4][8];
    #pragma unroll
    for (int r = 0; r < 4; ++r)
        #pragma unroll
        for (int hd = 0; hd < 8; ++hd) lp[r][hd] = 0.f;

    #pragma unroll
    for (int t = 0; t < 16; ++t) {
        int n = t * 16 + c;
        float g1v = G1[n];
        float cbv = BB[n] + b1[n];
        float4 w2a = *(const float4*)(W2 + n * 8);
        float4 w2b = *(const float4*)(W2 + n * 8 + 4);
        #pragma unroll
        for (int r = 0; r < 4; ++r) {
            float v = fmaf(rstd_r[r], acc[t][r], fmaf(nmr_r[r], g1v, cbv));
            float h = v / (1.f + __expf(-v));   // silu
            lp[r][0] = fmaf(h, w2a.x, lp[r][0]);
            lp[r][1] = fmaf(h, w2a.y, lp[r][1]);
            lp[r][2] = fmaf(h, w2a.z, lp[r][2]);
            lp[r][3] = fmaf(h, w2a.w, lp[r][3]);
            lp[r][4] = fmaf(h, w2b.x, lp[r][4]);
            lp[r][5] = fmaf(h, w2b.y, lp[r][5]);
            lp[r][6] = fmaf(h, w2b.z, lp[r][6]);
            lp[r][7] = fmaf(h, w2b.w, lp[r][7]);
        }
    }
    #pragma unroll
    for (int m = 1; m < 16; m <<= 1)
        #pragma unroll
        for (int r = 0; r < 4; ++r)
            #pragma unroll
            for (int hd = 0; hd < 8; ++hd)
                lp[r][hd] += __shfl_xor(lp[r][hd], m);

    if (c == 0) {
        float4 b2a = *(const float4*)b2;
        float4 b2b = *(const float4*)(b2 + 4);
        #pragma unroll
        for (int r = 0; r < 4; ++r) {
            int orow = rowbase + q * 4 + r;   // D layout: row = quad*4 + reg
            float4 o0 = {lp[r][0] + b2a.x, lp[r][1] + b2a.y,
                         lp[r][2] + b2a.z, lp[r][3] + b2a.w};
            float4 o1 = {lp[r][4] + b2b.x, lp[r][5] + b2b.y,
                         lp[r][6] + b2b.z, lp[r][7] + b2b.w};
            *(float4*)(logits + (size_t)orow * 8) = o0;
            *(float4*)(logits + (size_t)orow * 8 + 4) = o1;
        }
    }
}

// ---------------- kernel 3a: per-graph softmax stats (max + sum tables) ----------------
__global__ __launch_bounds__(256) void k_smax(
    const float* __restrict__ logits, const int* __restrict__ seg,
    float* __restrict__ smaxt, float* __restrict__ sinvt)
{
    const int g = blockIdx.x;
    const int tid = threadIdx.x;
    const int s = seg[g], e = seg[g + 1];
    __shared__ float red[4][8];
    __shared__ float smx[8];
    const int wid = tid >> 6, lane = tid & 63;

    if (e <= s) {
        if (tid < 8) { smaxt[g * 8 + tid] = 0.f; sinvt[g * 8 + tid] = 1.f; }
        return;
    }
    float mx[8];
    #pragma unroll
    for (int h = 0; h < 8; ++h) mx[h] = -1e30f;
    for (int i = s + tid; i < e; i += 256) {
        float4 l0 = *(const float4*)(logits + (size_t)i * 8);
        float4 l1 = *(const float4*)(logits + (size_t)i * 8 + 4);
        mx[0] = fmaxf(mx[0], l0.x); mx[1] = fmaxf(mx[1], l0.y);
        mx[2] = fmaxf(mx[2], l0.z); mx[3] = fmaxf(mx[3], l0.w);
        mx[4] = fmaxf(mx[4], l1.x); mx[5] = fmaxf(mx[5], l1.y);
        mx[6] = fmaxf(mx[6], l1.z); mx[7] = fmaxf(mx[7], l1.w);
    }
    #pragma unroll
    for (int m = 1; m < 64; m <<= 1)
        #pragma unroll
        for (int h = 0; h < 8; ++h) mx[h] = fmaxf(mx[h], __shfl_xor(mx[h], m));
    if (lane == 0) {
        #pragma unroll
        for (int h = 0; h < 8; ++h) red[wid][h] = mx[h];
    }
    __syncthreads();
    if (tid < 8)
        smx[tid] = fmaxf(fmaxf(red[0][tid], red[1][tid]),
                         fmaxf(red[2][tid], red[3][tid]));
    __syncthreads();
    float sm[8];
    #pragma unroll
    for (int h = 0; h < 8; ++h) sm[h] = smx[h];
    float su[8] = {0, 0, 0, 0, 0, 0, 0, 0};
    for (int i = s + tid; i < e; i += 256) {
        float4 l0 = *(const float4*)(logits + (size_t)i * 8);
        float4 l1 = *(const float4*)(logits + (size_t)i * 8 + 4);
        su[0] += __expf(l0.x - sm[0]); su[1] += __expf(l0.y - sm[1]);
        su[2] += __expf(l0.z - sm[2]); su[3] += __expf(l0.w - sm[3]);
        su[4] += __expf(l1.x - sm[4]); su[5] += __expf(l1.y - sm[5]);
        su[6] += __expf(l1.z - sm[6]); su[7] += __expf(l1.w - sm[7]);
    }
    #pragma unroll
    for (int m = 1; m < 64; m <<= 1)
        #pragma unroll
        for (int h = 0; h < 8; ++h) su[h] += __shfl_xor(su[h], m);
    if (lane == 0) {
        #pragma unroll
        for (int h = 0; h < 8; ++h) red[wid][h] = su[h];
    }
    __syncthreads();
    if (tid < 8) {
        float d = red[0][tid] + red[1][tid] + red[2][tid] + red[3][tid];
        smaxt[g * 8 + tid] = smx[tid];
        sinvt[g * 8 + tid] = 1.f / (d > 0.f ? d : 1.f);
    }
}

// ---------------- kernel 3b: weights + entropy (row-parallel, coalesced) ----------------
__global__ __launch_bounds__(256) void k_wts(
    const float* __restrict__ logits, const int* __restrict__ batch,
    const float* __restrict__ smaxt, const float* __restrict__ sinvt,
    float* __restrict__ weights, float* __restrict__ ent)
{
    const int tid = threadIdx.x;
    const int i0 = blockIdx.x * 256;
    const int h = tid & 7;
    float e = 0.f;
    #pragma unroll
    for (int it = 0; it < 8; ++it) {
        int i = i0 + (tid >> 3) + it * 32;
        int g = batch[i];
        float l = logits[(size_t)i * 8 + h];
        float w = __expf(l - smaxt[g * 8 + h]) * sinvt[g * 8 + h];
        weights[(size_t)i * 8 + h] = w;
        e += w * __logf(w + 1e-8f);
    }
    #pragma unroll
    for (int m = 1; m < 64; m <<= 1) e += __shfl_xor(e, m);
    __shared__ float red[4];
    if ((tid & 63) == 0) red[tid >> 6] = e;
    __syncthreads();
    if (tid == 0)
        atomicAdd(ent, (red[0] + red[1] + red[2] + red[3]) * (-1.f / (GNUM * 8.f)));
}

// ---------------- kernel 3c: weighted pooling, row-chunked scatter-add ----------------
__global__ __launch_bounds__(256) void k_pool2(
    const float* __restrict__ x, const int* __restrict__ batch,
    const float* __restrict__ weights, float* __restrict__ graph_z)
{
    const int tid = threadIdx.x;
    const int r0 = blockIdx.x * POOL_ROWS;
    const int h = tid >> 5;
    const int f = tid * 2;
    float a0 = 0.f, a1 = 0.f;
    int gcur = batch[r0];
    const int gend = batch[r0 + POOL_ROWS - 1];

    if (gcur == gend) {
        #pragma unroll 4
        for (int r = 0; r < POOL_ROWS; ++r) {
            const size_t i = (size_t)(r0 + r);
            float2 xv = *(const float2*)(x + i * HID + f);
            float w = weights[i * 8 + h];
            a0 = fmaf(xv.x, w, a0);
            a1 = fmaf(xv.y, w, a1);
        }
        atomicAdd(graph_z + (size_t)gcur * HID + f, a0);
        atomicAdd(graph_z + (size_t)gcur * HID + f + 1, a1);
    } else {
        for (int r = 0; r < POOL_ROWS; ++r) {
            const int i = r0 + r;
            const int g = batch[i];
            if (g != gcur) {
                atomicAdd(graph_z + (size_t)gcur * HID + f, a0);
                atomicAdd(graph_z + (size_t)gcur * HID + f + 1, a1);
                a0 = 0.f; a1 = 0.f; gcur = g;
            }
            float2 xv = *(const float2*)(x + (size_t)i * HID + f);
            float w = weights[(size_t)i * 8 + h];
            a0 = fmaf(xv.x, w, a0);
            a1 = fmaf(xv.y, w, a1);
        }
        atomicAdd(graph_z + (size_t)gcur * HID + f, a0);
        atomicAdd(graph_z + (size_t)gcur * HID + f + 1, a1);
    }
}

extern "C" void kernel_launch(void* const* d_in, const int* in_sizes, int n_in,
                              void* d_out, int out_size, void* d_ws, size_t ws_size,
                              hipStream_t stream)
{
    const float* x     = (const float*)d_in[0];
    const int*   batch = (const int*)d_in[1];
    const float* gamma = (const float*)d_in[2];
    const float* beta  = (const float*)d_in[3];
    const float* W1    = (const float*)d_in[4];
    const float* b1    = (const float*)d_in[5];
    const float* W2    = (const float*)d_in[6];
    const float* b2    = (const float*)d_in[7];

    char* ws = (char*)d_ws;
    float*  logits = (float*)ws;                                    // 8 MB
    __bf16* w1t    = (__bf16*)(ws + (size_t)8 * 1024 * 1024);       // 256 KB
    int*    seg    = (int*)(ws + (size_t)8 * 1024 * 1024 + 256 * 1024);   // 4.1 KB
    float*  G1     = (float*)(ws + (size_t)8 * 1024 * 1024 + 272 * 1024); // 1 KB
    float*  BB     = (float*)(ws + (size_t)8 * 1024 * 1024 + 276 * 1024); // 1 KB
    float*  smaxt  = (float*)(ws + (size_t)8 * 1024 * 1024 + 288 * 1024); // 32 KB
    float*  sinvt  = (float*)(ws + (size_t)8 * 1024 * 1024 + 320 * 1024); // 32 KB

    float* out     = (float*)d_out;
    float* graph_z = out;                                           // [G,512]
    float* weights = out + (size_t)GNUM * HID;                      // [N,8]
    float* ent     = out + (size_t)GNUM * HID + (size_t)N_ROWS * HEADS; // scalar

    k_prep <<<512, 256, 0, stream>>>(W1, gamma, w1t, ent, graph_z, G1, BB);
    k_cols <<<8, 256, 0, stream>>>(W1, gamma, beta, G1, BB);
    k_seg  <<<5, 256, 0, stream>>>(batch, seg);
    k_gemm <<<N_ROWS / 64, 256, 0, stream>>>(x, w1t, b1, G1, BB, W2, b2, logits);
    k_smax <<<GNUM, 256, 0, stream>>>(logits, seg, smaxt, sinvt);
    k_wts  <<<N_ROWS / 256, 256, 0, stream>>>(logits, batch, smaxt, sinvt, weights, ent);
    k_pool2<<<N_ROWS / POOL_ROWS, 256, 0, stream>>>(x, batch, weights, graph_z);
}